// Round 1
// baseline (2896.587 us; speedup 1.0000x reference)
//
#include <hip/hip_runtime.h>

#define BB 8
#define NN 512
#define TT 64
#define DD 128
#define HH 8
#define DKK 16
#define KK 3
#define PIN 130   // bf16 pitch for s_in: bank=(t + din/2)%32 over lane=t -> conflict-free
#define PKV 136   // bf16 pitch for s_k/s_v: rows 272B (16B-aligned) for uint4 reads

__device__ __forceinline__ float bflo(unsigned int p){ return __uint_as_float(p << 16); }
__device__ __forceinline__ float bfhi(unsigned int p){ return __uint_as_float(p & 0xffff0000u); }
__device__ __forceinline__ unsigned short f2bf(float f){
  unsigned int u = __float_as_uint(f);
  u += 0x7fffu + ((u >> 16) & 1u);   // RNE
  return (unsigned short)(u >> 16);
}

__global__ __launch_bounds__(512)
void fused_mhatc(const float* __restrict__ query, const float* __restrict__ key_,
                 const float* __restrict__ value, const int* __restrict__ mask,
                 const float* __restrict__ Wq, const float* __restrict__ bq,
                 const float* __restrict__ Wk, const float* __restrict__ bk,
                 const float* __restrict__ Wv, const float* __restrict__ bv,
                 const float* __restrict__ Wo, const float* __restrict__ bo,
                 float* __restrict__ out)
{
  __shared__ __align__(16) unsigned short s_in[(TT+2)*PIN];
  __shared__ __align__(16) unsigned short s_k[TT*PKV];
  __shared__ __align__(16) unsigned short s_v[TT*PKV];

  const int tid = threadIdx.x;
  const int t   = tid & 63;
  const int wg  = __builtin_amdgcn_readfirstlane(tid >> 6); // 0..7, wave-uniform -> SGPR
  const int d0  = wg * 16;
  const int bn  = blockIdx.x;        // b*N + n
  const int b   = bn >> 9;           // N = 512
  const size_t base = (size_t)bn * (TT*DD);

  // ---------- phase 1: stage query (bf16) into rows 2..65, zero rows 0..1 ----------
  for (int i = tid; i < 2*PIN; i += 512) s_in[i] = 0;
  for (int i = tid; i < (TT*DD)/4; i += 512) {
    float4 v4 = ((const float4*)(query + base))[i];
    int r = (i >> 5) + 2, c = (i & 31) * 4;
    unsigned int p0 = (unsigned int)f2bf(v4.x) | ((unsigned int)f2bf(v4.y) << 16);
    unsigned int p1 = (unsigned int)f2bf(v4.z) | ((unsigned int)f2bf(v4.w) << 16);
    *(unsigned int*)&s_in[r*PIN + c]     = p0;
    *(unsigned int*)&s_in[r*PIN + c + 2] = p1;
  }
  __syncthreads();

  // ---------- phase 2: causal conv q -> registers (this thread IS head wg, row t) ----------
  float qv[16];
  {
    #pragma unroll
    for (int j = 0; j < 16; ++j) qv[j] = bq[d0 + j];
    const float* Wbase = Wq + d0 * (DD*KK);
    for (int din = 0; din < DD; din += 2) {
      unsigned int p0 = *(const unsigned int*)&s_in[(t+0)*PIN + din];
      unsigned int p1 = *(const unsigned int*)&s_in[(t+1)*PIN + din];
      unsigned int p2 = *(const unsigned int*)&s_in[(t+2)*PIN + din];
      float x00=bflo(p0), x01=bfhi(p0), x10=bflo(p1), x11=bfhi(p1), x20=bflo(p2), x21=bfhi(p2);
      #pragma unroll
      for (int j = 0; j < 16; ++j) {
        const float* w = Wbase + j*(DD*KK) + din*KK;  // uniform -> s_load
        qv[j] = fmaf(w[0],x00, fmaf(w[1],x10, fmaf(w[2],x20,
                fmaf(w[3],x01, fmaf(w[4],x11, fmaf(w[5],x21, qv[j]))))));
      }
    }
  }
  __syncthreads();

  // ---------- phase 3: stage key rows 1..64 (zero rows 0, 65), same-pad conv k -> s_k ----------
  for (int i = tid; i < PIN; i += 512) { s_in[i] = 0; s_in[65*PIN + i] = 0; }
  for (int i = tid; i < (TT*DD)/4; i += 512) {
    float4 v4 = ((const float4*)(key_ + base))[i];
    int r = (i >> 5) + 1, c = (i & 31) * 4;
    unsigned int p0 = (unsigned int)f2bf(v4.x) | ((unsigned int)f2bf(v4.y) << 16);
    unsigned int p1 = (unsigned int)f2bf(v4.z) | ((unsigned int)f2bf(v4.w) << 16);
    *(unsigned int*)&s_in[r*PIN + c]     = p0;
    *(unsigned int*)&s_in[r*PIN + c + 2] = p1;
  }
  __syncthreads();
  {
    float acc[16];
    #pragma unroll
    for (int j = 0; j < 16; ++j) acc[j] = bk[d0 + j];
    const float* Wbase = Wk + d0 * (DD*KK);
    for (int din = 0; din < DD; din += 2) {
      unsigned int p0 = *(const unsigned int*)&s_in[(t+0)*PIN + din];
      unsigned int p1 = *(const unsigned int*)&s_in[(t+1)*PIN + din];
      unsigned int p2 = *(const unsigned int*)&s_in[(t+2)*PIN + din];
      float x00=bflo(p0), x01=bfhi(p0), x10=bflo(p1), x11=bfhi(p1), x20=bflo(p2), x21=bfhi(p2);
      #pragma unroll
      for (int j = 0; j < 16; ++j) {
        const float* w = Wbase + j*(DD*KK) + din*KK;
        acc[j] = fmaf(w[0],x00, fmaf(w[1],x10, fmaf(w[2],x20,
                 fmaf(w[3],x01, fmaf(w[4],x11, fmaf(w[5],x21, acc[j]))))));
      }
    }
    #pragma unroll
    for (int j2 = 0; j2 < 8; ++j2) {
      unsigned int p = (unsigned int)f2bf(acc[2*j2]) | ((unsigned int)f2bf(acc[2*j2+1]) << 16);
      *(unsigned int*)&s_k[t*PKV + d0 + 2*j2] = p;
    }
  }
  __syncthreads();

  // ---------- phase 4: stage value rows 0..63, v = value @ Wv^T + bv -> s_v ----------
  for (int i = tid; i < (TT*DD)/4; i += 512) {
    float4 v4 = ((const float4*)(value + base))[i];
    int r = (i >> 5), c = (i & 31) * 4;
    unsigned int p0 = (unsigned int)f2bf(v4.x) | ((unsigned int)f2bf(v4.y) << 16);
    unsigned int p1 = (unsigned int)f2bf(v4.z) | ((unsigned int)f2bf(v4.w) << 16);
    *(unsigned int*)&s_in[r*PIN + c]     = p0;
    *(unsigned int*)&s_in[r*PIN + c + 2] = p1;
  }
  __syncthreads();
  {
    float acc[16];
    #pragma unroll
    for (int j = 0; j < 16; ++j) acc[j] = bv[d0 + j];
    for (int din = 0; din < DD; din += 2) {
      unsigned int p = *(const unsigned int*)&s_in[t*PIN + din];
      float xl = bflo(p), xh = bfhi(p);
      #pragma unroll
      for (int j = 0; j < 16; ++j) {
        const float* w = Wv + (d0+j)*DD + din;   // uniform -> s_load
        acc[j] = fmaf(w[0], xl, fmaf(w[1], xh, acc[j]));
      }
    }
    #pragma unroll
    for (int j2 = 0; j2 < 8; ++j2) {
      unsigned int p = (unsigned int)f2bf(acc[2*j2]) | ((unsigned int)f2bf(acc[2*j2+1]) << 16);
      *(unsigned int*)&s_v[t*PKV + d0 + 2*j2] = p;
    }
  }
  __syncthreads();

  // ---------- phase 5: attention, head h = wg, row t ----------
  {
    const int h = wg;
    float sc[64];
    float mx = -3.0e38f;
    const int* mrow = mask + ((size_t)b*TT + t)*TT;
    #pragma unroll
    for (int s4 = 0; s4 < 16; ++s4) {
      int4 m4 = ((const int4*)mrow)[s4];
      int mm[4] = {m4.x, m4.y, m4.z, m4.w};
      #pragma unroll
      for (int u = 0; u < 4; ++u) {
        int s = s4*4 + u;
        const unsigned short* kr = &s_k[s*PKV + h*16];
        uint4 ra = *(const uint4*)kr;
        uint4 rb = *(const uint4*)(kr + 8);
        float a;
        a  = qv[0]*bflo(ra.x) + qv[1]*bfhi(ra.x);
        a += qv[2]*bflo(ra.y) + qv[3]*bfhi(ra.y);
        a += qv[4]*bflo(ra.z) + qv[5]*bfhi(ra.z);
        a += qv[6]*bflo(ra.w) + qv[7]*bfhi(ra.w);
        a += qv[8]*bflo(rb.x) + qv[9]*bfhi(rb.x);
        a += qv[10]*bflo(rb.y) + qv[11]*bfhi(rb.y);
        a += qv[12]*bflo(rb.z) + qv[13]*bfhi(rb.z);
        a += qv[14]*bflo(rb.w) + qv[15]*bfhi(rb.w);
        a *= 0.25f;                       // 1/sqrt(DK)
        a = (mm[u] == 0) ? -1.0e9f : a;
        sc[s] = a;
        mx = fmaxf(mx, a);
      }
    }
    float sum = 0.f;
    #pragma unroll
    for (int s = 0; s < TT; ++s) { float e = __expf(sc[s] - mx); sc[s] = e; sum += e; }
    const float inv = 1.0f / sum;
    float xa[16];
    #pragma unroll
    for (int j = 0; j < 16; ++j) xa[j] = 0.f;
    #pragma unroll
    for (int s = 0; s < TT; ++s) {
      float p = sc[s] * inv;
      const unsigned short* vr = &s_v[s*PKV + h*16];
      uint4 ra = *(const uint4*)vr;
      uint4 rb = *(const uint4*)(vr + 8);
      xa[0]  = fmaf(p, bflo(ra.x), xa[0]);  xa[1]  = fmaf(p, bfhi(ra.x), xa[1]);
      xa[2]  = fmaf(p, bflo(ra.y), xa[2]);  xa[3]  = fmaf(p, bfhi(ra.y), xa[3]);
      xa[4]  = fmaf(p, bflo(ra.z), xa[4]);  xa[5]  = fmaf(p, bfhi(ra.z), xa[5]);
      xa[6]  = fmaf(p, bflo(ra.w), xa[6]);  xa[7]  = fmaf(p, bfhi(ra.w), xa[7]);
      xa[8]  = fmaf(p, bflo(rb.x), xa[8]);  xa[9]  = fmaf(p, bfhi(rb.x), xa[9]);
      xa[10] = fmaf(p, bflo(rb.y), xa[10]); xa[11] = fmaf(p, bfhi(rb.y), xa[11]);
      xa[12] = fmaf(p, bflo(rb.z), xa[12]); xa[13] = fmaf(p, bfhi(rb.z), xa[13]);
      xa[14] = fmaf(p, bflo(rb.w), xa[14]); xa[15] = fmaf(p, bfhi(rb.w), xa[15]);
    }
    // x[t][h*16+dk] -> s_in (raw inputs no longer needed)
    #pragma unroll
    for (int j2 = 0; j2 < 8; ++j2) {
      unsigned int p = (unsigned int)f2bf(xa[2*j2]) | ((unsigned int)f2bf(xa[2*j2+1]) << 16);
      *(unsigned int*)&s_in[t*PIN + h*16 + 2*j2] = p;
    }
  }
  __syncthreads();

  // ---------- phase 6: out = x @ Wo^T + bo ----------
  {
    float acc[16];
    #pragma unroll
    for (int j = 0; j < 16; ++j) acc[j] = bo[d0 + j];
    for (int din = 0; din < DD; din += 2) {
      unsigned int p = *(const unsigned int*)&s_in[t*PIN + din];
      float xl = bflo(p), xh = bfhi(p);
      #pragma unroll
      for (int j = 0; j < 16; ++j) {
        const float* w = Wo + (d0+j)*DD + din;   // uniform -> s_load
        acc[j] = fmaf(w[0], xl, fmaf(w[1], xh, acc[j]));
      }
    }
    float* orow = out + base + t*DD + d0;
    ((float4*)orow)[0] = make_float4(acc[0], acc[1], acc[2], acc[3]);
    ((float4*)orow)[1] = make_float4(acc[4], acc[5], acc[6], acc[7]);
    ((float4*)orow)[2] = make_float4(acc[8], acc[9], acc[10], acc[11]);
    ((float4*)orow)[3] = make_float4(acc[12], acc[13], acc[14], acc[15]);
  }
}

extern "C" void kernel_launch(void* const* d_in, const int* in_sizes, int n_in,
                              void* d_out, int out_size, void* d_ws, size_t ws_size,
                              hipStream_t stream) {
  (void)in_sizes; (void)n_in; (void)out_size; (void)d_ws; (void)ws_size;
  const float* query = (const float*)d_in[0];
  const float* key_  = (const float*)d_in[1];
  const float* value = (const float*)d_in[2];
  const int*   mask  = (const int*)d_in[3];
  const float* Wq = (const float*)d_in[4];
  const float* bq = (const float*)d_in[5];
  const float* Wk = (const float*)d_in[6];
  const float* bk = (const float*)d_in[7];
  const float* Wv = (const float*)d_in[8];
  const float* bv = (const float*)d_in[9];
  const float* Wo = (const float*)d_in[10];
  const float* bo = (const float*)d_in[11];
  float* out = (float*)d_out;
  hipLaunchKernelGGL(fused_mhatc, dim3(BB*NN), dim3(512), 0, stream,
                     query, key_, value, mask, Wq, bq, Wk, bk, Wv, bv, Wo, bo, out);
}

// Round 2
// 496.784 us; speedup vs baseline: 5.8307x; 5.8307x over previous
//
#include <hip/hip_runtime.h>

#define TT 64
#define DD 128
#define SMEM_B 68608   // 17408 (s_in 64x136 bf16) + 8 waves * 6400 (q 2048 | k 2048 | vT 16x72=2304; p 16x40 overlays q)

typedef short short8 __attribute__((ext_vector_type(8)));
typedef float floatx4 __attribute__((ext_vector_type(4)));

union U16 { uint4 u4; short8 s8; };
__device__ __forceinline__ short8 u4s8(uint4 v){ U16 u; u.u4 = v; return u.s8; }

__device__ __forceinline__ unsigned short f2bf(float f){
  unsigned int u = __float_as_uint(f);
  u += 0x7fffu + ((u >> 16) & 1u);   // RNE
  return (unsigned short)(u >> 16);
}

// ---------------- weight pre-swizzle into exact B-fragment order ----------------
// conv B (per conv): [kt(12)][w(8)][lane(64)][j(8)] = W[dout=w*16+(lane&15)][din=(kt&3)*32+(lane>>4)*8+j][kk=kt>>2]
// proj B:            [kt(4)][w(8)][lane(64)][j(8)]  = W[e=w*16+(lane&15)][d=kt*32+(lane>>4)*8+j]
__global__ void prep_w(const float* __restrict__ Wq, const float* __restrict__ Wk,
                       const float* __restrict__ Wv, const float* __restrict__ Wo,
                       unsigned short* __restrict__ ws)
{
  int gid = blockIdx.x*256 + threadIdx.x;            // 16384 threads
  unsigned int pk[4];
  unsigned short* dst;
  if (gid < 12288) {
    int mat = gid / 6144, r = gid % 6144;
    int kt = r >> 9, w = (r >> 6) & 7, lane = r & 63;
    int c = lane & 15, quad = lane >> 4;
    int dout = w*16 + c, kk = kt >> 2, din0 = (kt & 3)*32 + quad*8;
    const float* W = mat ? Wk : Wq;
    #pragma unroll
    for (int j2 = 0; j2 < 4; ++j2) {
      unsigned int lo = f2bf(W[dout*384 + (din0+2*j2  )*3 + kk]);
      unsigned int hi = f2bf(W[dout*384 + (din0+2*j2+1)*3 + kk]);
      pk[j2] = lo | (hi << 16);
    }
    dst = ws + (mat ? 49152 : 0) + (size_t)((kt*8 + w)*64 + lane)*8;
  } else {
    int p = gid - 12288;
    int mat = p / 2048, r = p % 2048;
    int kt = r >> 9, w = (r >> 6) & 7, lane = r & 63;
    int c = lane & 15, quad = lane >> 4;
    int e = w*16 + c, d0 = kt*32 + quad*8;
    const float* W = mat ? Wo : Wv;
    #pragma unroll
    for (int j2 = 0; j2 < 4; ++j2) {
      unsigned int lo = f2bf(W[e*128 + d0 + 2*j2]);
      unsigned int hi = f2bf(W[e*128 + d0 + 2*j2 + 1]);
      pk[j2] = lo | (hi << 16);
    }
    dst = ws + (mat ? 114688 : 98304) + (size_t)((kt*8 + w)*64 + lane)*8;
  }
  *(uint4*)dst = make_uint4(pk[0], pk[1], pk[2], pk[3]);
}

// ---------------- fused main kernel: one block per (b,n) ----------------
__global__ __launch_bounds__(512, 4)
void fused_mfma(const float* __restrict__ query, const float* __restrict__ key_,
                const float* __restrict__ value, const int* __restrict__ mask,
                const float* __restrict__ bq, const float* __restrict__ bk,
                const float* __restrict__ bv, const float* __restrict__ bo,
                const unsigned short* __restrict__ wsw,
                float* __restrict__ out)
{
  extern __shared__ char smem[];
  unsigned short* s_in = (unsigned short*)smem;                 // 64 x 136 bf16 (staging, later x)
  const int tid  = threadIdx.x;
  const int lane = tid & 63;
  const int c    = lane & 15;
  const int quad = lane >> 4;
  const int w    = __builtin_amdgcn_readfirstlane(tid >> 6);    // wave id = head id = n-tile
  unsigned short* wscr  = (unsigned short*)(smem + 17408 + w*6400);
  unsigned short* q_scr = wscr;          // 64x16
  unsigned short* k_scr = wscr + 1024;   // 64x16
  unsigned short* v_scr = wscr + 2048;   // 16x72 transposed: v_scr[dk][s]
  unsigned short* p_scr = wscr;          // 16x40, overlays q_scr (q dead by then)

  const int bn = blockIdx.x;
  const int b  = bn >> 9;
  const size_t base = (size_t)bn * (TT*DD);

  const unsigned short* WqB = wsw;
  const unsigned short* WkB = wsw + 49152;
  const unsigned short* WvB = wsw + 98304;
  const unsigned short* WoB = wsw + 114688;

  const floatx4 zf = {0.f, 0.f, 0.f, 0.f};

  auto stage = [&](const float* src){
    #pragma unroll
    for (int i = 0; i < 4; ++i) {
      int idx = tid + i*512;                       // 2048 float4
      float4 v4 = ((const float4*)src)[idx];
      int r = idx >> 5, cc = (idx & 31)*4;
      unsigned int p0 = (unsigned int)f2bf(v4.x) | ((unsigned int)f2bf(v4.y) << 16);
      unsigned int p1 = (unsigned int)f2bf(v4.z) | ((unsigned int)f2bf(v4.w) << 16);
      *(unsigned int*)&s_in[r*136 + cc]     = p0;
      *(unsigned int*)&s_in[r*136 + cc + 2] = p1;
    }
  };

  auto conv = [&](const unsigned short* WB, const float* bias, unsigned short* dst, int pad){
    float bb = bias[w*16 + c];
    floatx4 acc[4];
    #pragma unroll
    for (int mt = 0; mt < 4; ++mt) acc[mt] = (floatx4){bb, bb, bb, bb};
    #pragma unroll
    for (int kt = 0; kt < 12; ++kt) {
      short8 bf = u4s8(*(const uint4*)&WB[(size_t)((kt*8 + w)*64 + lane)*8]);
      const int kk = kt >> 2;
      const int din0 = (kt & 3)*32 + quad*8;
      #pragma unroll
      for (int mt = 0; mt < 4; ++mt) {
        int row = mt*16 + c + kk - pad;
        uint4 a4 = make_uint4(0,0,0,0);
        if (row >= 0 && row < 64) a4 = *(const uint4*)&s_in[row*136 + din0];
        acc[mt] = __builtin_amdgcn_mfma_f32_16x16x32_bf16(u4s8(a4), bf, acc[mt], 0, 0, 0);
      }
    }
    #pragma unroll
    for (int mt = 0; mt < 4; ++mt)
      #pragma unroll
      for (int r = 0; r < 4; ++r)
        dst[(mt*16 + quad*4 + r)*16 + c] = f2bf(acc[mt][r]);
  };

  // ---- phase 1/2: query staging + causal conv -> q_scr ----
  stage(query + base);
  __syncthreads();
  conv(WqB, bq, q_scr, 2);
  __syncthreads();

  // ---- phase 3/4: key staging + same-pad conv -> k_scr ----
  stage(key_ + base);
  __syncthreads();
  conv(WkB, bk, k_scr, 1);
  __syncthreads();

  // ---- phase 5/6: value staging + v-proj -> v_scr (transposed) ----
  stage(value + base);
  __syncthreads();
  {
    float bb = bv[w*16 + c];
    floatx4 acc[4];
    #pragma unroll
    for (int mt = 0; mt < 4; ++mt) acc[mt] = (floatx4){bb, bb, bb, bb};
    #pragma unroll
    for (int kt = 0; kt < 4; ++kt) {
      short8 bf = u4s8(*(const uint4*)&WvB[(size_t)((kt*8 + w)*64 + lane)*8]);
      const int din0 = kt*32 + quad*8;
      #pragma unroll
      for (int mt = 0; mt < 4; ++mt) {
        uint4 a4 = *(const uint4*)&s_in[(mt*16 + c)*136 + din0];
        acc[mt] = __builtin_amdgcn_mfma_f32_16x16x32_bf16(u4s8(a4), bf, acc[mt], 0, 0, 0);
      }
    }
    #pragma unroll
    for (int mt = 0; mt < 4; ++mt)
      #pragma unroll
      for (int r = 0; r < 4; ++r)
        v_scr[c*72 + mt*16 + quad*4 + r] = f2bf(acc[mt][r]);
  }
  __syncthreads();   // all waves done reading s_in -> it may now become x_buf

  // ---- phase 7: attention, head = w (fully wave-private) ----
  {
    short8 aq[4], bk4[4];
    #pragma unroll
    for (int mt = 0; mt < 4; ++mt) {
      uint4 t4 = make_uint4(0,0,0,0);
      if (quad < 2) t4 = *(const uint4*)&q_scr[(mt*16 + c)*16 + quad*8];
      aq[mt] = u4s8(t4);
    }
    #pragma unroll
    for (int nt = 0; nt < 4; ++nt) {
      uint4 t4 = make_uint4(0,0,0,0);
      if (quad < 2) t4 = *(const uint4*)&k_scr[(nt*16 + c)*16 + quad*8];
      bk4[nt] = u4s8(t4);
    }
    __asm__ volatile("" ::: "memory");   // q/k frag reads stay before p_scr overlay writes
    const int* mrow = mask + b*4096;

    #pragma unroll
    for (int mt = 0; mt < 4; ++mt) {
      floatx4 S[4];
      #pragma unroll
      for (int nt = 0; nt < 4; ++nt)
        S[nt] = __builtin_amdgcn_mfma_f32_16x16x32_bf16(aq[mt], bk4[nt], zf, 0, 0, 0);

      float sc[4][4], mx[4];
      #pragma unroll
      for (int r = 0; r < 4; ++r) mx[r] = -3.0e38f;
      #pragma unroll
      for (int nt = 0; nt < 4; ++nt)
        #pragma unroll
        for (int r = 0; r < 4; ++r) {
          int t_r = mt*16 + quad*4 + r, s_c = nt*16 + c;
          float v = S[nt][r] * 0.25f;                 // 1/sqrt(16)
          if (mrow[t_r*64 + s_c] == 0) v = -1.0e9f;
          sc[nt][r] = v;
          mx[r] = fmaxf(mx[r], v);
        }
      #pragma unroll
      for (int r = 0; r < 4; ++r) {
        mx[r] = fmaxf(mx[r], __shfl_xor(mx[r], 1));
        mx[r] = fmaxf(mx[r], __shfl_xor(mx[r], 2));
        mx[r] = fmaxf(mx[r], __shfl_xor(mx[r], 4));
        mx[r] = fmaxf(mx[r], __shfl_xor(mx[r], 8));
      }
      float sm[4] = {0.f, 0.f, 0.f, 0.f};
      #pragma unroll
      for (int nt = 0; nt < 4; ++nt)
        #pragma unroll
        for (int r = 0; r < 4; ++r) {
          float e = exp2f((sc[nt][r] - mx[r]) * 1.44269504f);
          sc[nt][r] = e;
          sm[r] += e;
        }
      #pragma unroll
      for (int r = 0; r < 4; ++r) {
        sm[r] += __shfl_xor(sm[r], 1);
        sm[r] += __shfl_xor(sm[r], 2);
        sm[r] += __shfl_xor(sm[r], 4);
        sm[r] += __shfl_xor(sm[r], 8);
      }
      float inv[4];
      #pragma unroll
      for (int r = 0; r < 4; ++r) inv[r] = 1.0f / sm[r];

      floatx4 X = zf;
      #pragma unroll
      for (int kt = 0; kt < 2; ++kt) {
        #pragma unroll
        for (int nt2 = 0; nt2 < 2; ++nt2) {
          int nt = kt*2 + nt2;
          #pragma unroll
          for (int r = 0; r < 4; ++r)
            p_scr[(quad*4 + r)*40 + nt2*16 + c] = f2bf(sc[nt][r] * inv[r]);
        }
        __asm__ volatile("s_waitcnt lgkmcnt(0)" ::: "memory");
        uint4 ap4 = *(const uint4*)&p_scr[c*40 + quad*8];
        uint4 bv4 = *(const uint4*)&v_scr[c*72 + kt*32 + quad*8];
        X = __builtin_amdgcn_mfma_f32_16x16x32_bf16(u4s8(ap4), u4s8(bv4), X, 0, 0, 0);
      }
      #pragma unroll
      for (int r = 0; r < 4; ++r)
        s_in[(mt*16 + quad*4 + r)*136 + w*16 + c] = f2bf(X[r]);   // x_buf
    }
  }
  __syncthreads();

  // ---- phase 8: out = x @ Wo^T + bo ----
  {
    float bb = bo[w*16 + c];
    floatx4 acc[4];
    #pragma unroll
    for (int mt = 0; mt < 4; ++mt) acc[mt] = (floatx4){bb, bb, bb, bb};
    #pragma unroll
    for (int kt = 0; kt < 4; ++kt) {
      short8 bf = u4s8(*(const uint4*)&WoB[(size_t)((kt*8 + w)*64 + lane)*8]);
      const int din0 = kt*32 + quad*8;
      #pragma unroll
      for (int mt = 0; mt < 4; ++mt) {
        uint4 a4 = *(const uint4*)&s_in[(mt*16 + c)*136 + din0];
        acc[mt] = __builtin_amdgcn_mfma_f32_16x16x32_bf16(u4s8(a4), bf, acc[mt], 0, 0, 0);
      }
    }
    #pragma unroll
    for (int mt = 0; mt < 4; ++mt)
      #pragma unroll
      for (int r = 0; r < 4; ++r)
        out[base + (size_t)(mt*16 + quad*4 + r)*128 + w*16 + c] = acc[mt][r];
  }
}

extern "C" void kernel_launch(void* const* d_in, const int* in_sizes, int n_in,
                              void* d_out, int out_size, void* d_ws, size_t ws_size,
                              hipStream_t stream) {
  (void)in_sizes; (void)n_in; (void)out_size; (void)ws_size;
  const float* query = (const float*)d_in[0];
  const float* key_  = (const float*)d_in[1];
  const float* value = (const float*)d_in[2];
  const int*   mask  = (const int*)d_in[3];
  const float* Wq = (const float*)d_in[4];
  const float* bq = (const float*)d_in[5];
  const float* Wk = (const float*)d_in[6];
  const float* bk = (const float*)d_in[7];
  const float* Wv = (const float*)d_in[8];
  const float* bv = (const float*)d_in[9];
  const float* Wo = (const float*)d_in[10];
  const float* bo = (const float*)d_in[11];
  float* out = (float*)d_out;
  unsigned short* ws = (unsigned short*)d_ws;

  static int smem_set = -1;  // host-side cache only; same work every call (idempotent attribute)
  if (smem_set != SMEM_B) {
    hipFuncSetAttribute((const void*)fused_mfma,
                        hipFuncAttributeMaxDynamicSharedMemorySize, SMEM_B);
    smem_set = SMEM_B;
  }

  hipLaunchKernelGGL(prep_w, dim3(64), dim3(256), 0, stream, Wq, Wk, Wv, Wo, ws);
  hipLaunchKernelGGL(fused_mfma, dim3(8*512), dim3(512), SMEM_B, stream,
                     query, key_, value, mask, bq, bk, bv, bo, ws, out);
}